// Round 1
// baseline (6362.748 us; speedup 1.0000x reference)
//
#include <hip/hip_runtime.h>
#include <cstdint>
#include <cstddef>

#define NN 50000
#define NE 800000
// DN=128, DE=64, H=8, C=16

__device__ __forceinline__ float b2f(unsigned short s) {
  union { unsigned int u; float f; } x; x.u = ((unsigned int)s) << 16; return x.f;
}
__device__ __forceinline__ unsigned short f2b(float f) {
  union { float f; unsigned int u; } x; x.f = f;
  unsigned int r = x.u + 0x7FFFu + ((x.u >> 16) & 1u);
  return (unsigned short)(r >> 16);
}

// ---------------- ws layout (bytes) ----------------
#define WS_WCE   0u           // bf16 [64][128]  (16 KB, reserve 32K)
#define WS_BCE   32768u       // f32  [128]
#define WS_QB    65536u       // bf16 [NN][128]
#define WS_KB    12865536u    // bf16 [NN][128]
#define WS_VB    25665536u    // bf16 [NN][128]
#define WS_XR    38465536u    // f32  [NN][128]
#define WS_EB    64065536u    // bf16 [NE][128]
#define WS_EX    268865536u   // f32  [NE][8]
#define WS_DEN   294465536u   // f32  [NN][8]
#define WS_ATT   296065536u   // f32  [NN][128]
// total = 321,665,536 B

// W_ce = W_edge @ We  (64x128, bf16), b_ce = b_edge @ We (f32)
__global__ void k_prep(const float* __restrict__ W_edge, const float* __restrict__ b_edge,
                       const float* __restrict__ We, unsigned short* __restrict__ wce,
                       float* __restrict__ bce) {
  int i = blockIdx.x;       // 0..63
  int j = threadIdx.x;      // 0..127
  float s = 0.f;
  for (int m = 0; m < 64; ++m) s += W_edge[i*64+m] * We[m*128+j];
  wce[i*128+j] = f2b(s);
  if (i == 0) {
    float bb = 0.f;
    for (int m = 0; m < 64; ++m) bb += b_edge[m] * We[m*128+j];
    bce[j] = bb;
  }
}

// q,k,v (bf16) and x_r (f32): 32 nodes per block, 256 threads
__global__ void __launch_bounds__(256) k_node_lin(const float* __restrict__ x,
    const float* __restrict__ Wq, const float* __restrict__ bq,
    const float* __restrict__ Wk, const float* __restrict__ bk,
    const float* __restrict__ Wv, const float* __restrict__ bv,
    const float* __restrict__ Ws, const float* __restrict__ bs,
    unsigned short* __restrict__ q, unsigned short* __restrict__ k,
    unsigned short* __restrict__ v, float* __restrict__ xr) {
  __shared__ float xs[32][128];
  int n0 = blockIdx.x * 32;
  for (int idx = threadIdx.x; idx < 32*128; idx += 256) {
    int n = idx >> 7, c = idx & 127;
    xs[n][c] = (n0 + n < NN) ? x[(size_t)(n0+n)*128 + c] : 0.f;
  }
  __syncthreads();
  for (int p = 0; p < 2; ++p) {
    int pc = threadIdx.x + p*256;   // 0..511
    int mat = pc >> 7;              // 0..3
    int c = pc & 127;
    const float* W = (mat==0) ? Wq : (mat==1) ? Wk : (mat==2) ? Wv : Ws;
    const float* b = (mat==0) ? bq : (mat==1) ? bk : (mat==2) ? bv : bs;
    float acc[32];
    #pragma unroll
    for (int n = 0; n < 32; ++n) acc[n] = 0.f;
    for (int kk = 0; kk < 128; ++kk) {
      float w = W[kk*128 + c];
      #pragma unroll
      for (int n = 0; n < 32; ++n) acc[n] += xs[n][kk] * w;
    }
    float bias = b[c];
    for (int n = 0; n < 32; ++n) {
      int gn = n0 + n;
      if (gn < NN) {
        float val = acc[n] + bias;
        size_t o = (size_t)gn*128 + c;
        if (mat == 0)      q[o] = f2b(val);
        else if (mat == 1) k[o] = f2b(val);
        else if (mat == 2) v[o] = f2b(val);
        else               xr[o] = val;
      }
    }
  }
}

// e = edge_state @ W_ce + b_ce -> bf16 [NE][128]; 128-edge tile, 8x8 reg tile
__global__ void __launch_bounds__(256) k_egemm(const float* __restrict__ es,
    const unsigned short* __restrict__ wce, const float* __restrict__ bce,
    unsigned short* __restrict__ eb) {
  __shared__ float s_es[128][65];
  __shared__ unsigned short s_w[64][128];
  int e0 = blockIdx.x * 128;
  {
    const unsigned int* w32 = (const unsigned int*)wce;
    unsigned int* sw32 = (unsigned int*)s_w;
    for (int idx = threadIdx.x; idx < 4096; idx += 256) sw32[idx] = w32[idx];
  }
  for (int idx = threadIdx.x; idx < 128*64; idx += 256) {
    int r = idx >> 6, c = idx & 63;
    int ge = e0 + r;
    s_es[r][c] = (ge < NE) ? es[(size_t)ge*64 + c] : 0.f;
  }
  __syncthreads();
  int tr = threadIdx.x >> 4, tc = threadIdx.x & 15;
  int er0 = tr * 8, c0 = tc * 8;
  float acc[8][8];
  #pragma unroll
  for (int i = 0; i < 8; ++i)
    #pragma unroll
    for (int j = 0; j < 8; ++j) acc[i][j] = 0.f;
  for (int kk = 0; kk < 64; ++kk) {
    float wv[8];
    uint4 wq = *(const uint4*)&s_w[kk][c0];
    const unsigned int* wu = (const unsigned int*)&wq;
    #pragma unroll
    for (int j = 0; j < 4; ++j) {
      wv[2*j]   = b2f((unsigned short)(wu[j] & 0xffffu));
      wv[2*j+1] = b2f((unsigned short)(wu[j] >> 16));
    }
    float ev[8];
    #pragma unroll
    for (int i = 0; i < 8; ++i) ev[i] = s_es[er0+i][kk];
    #pragma unroll
    for (int i = 0; i < 8; ++i)
      #pragma unroll
      for (int j = 0; j < 8; ++j) acc[i][j] += ev[i] * wv[j];
  }
  #pragma unroll
  for (int i = 0; i < 8; ++i) {
    int ge = e0 + er0 + i;
    if (ge < NE) {
      unsigned short o[8];
      #pragma unroll
      for (int j = 0; j < 8; ++j) o[j] = f2b(acc[i][j] + bce[c0+j]);
      *(uint4*)&eb[(size_t)ge*128 + c0] = *(const uint4*)o;
    }
  }
}

__device__ __forceinline__ float dot8(uint4 q, uint4 k, uint4 e) {
  const unsigned int* qu = (const unsigned int*)&q;
  const unsigned int* ku = (const unsigned int*)&k;
  const unsigned int* eu = (const unsigned int*)&e;
  float s = 0.f;
  #pragma unroll
  for (int j = 0; j < 4; ++j) {
    float q0 = b2f((unsigned short)(qu[j] & 0xffffu)), q1 = b2f((unsigned short)(qu[j] >> 16));
    float k0 = b2f((unsigned short)(ku[j] & 0xffffu)), k1 = b2f((unsigned short)(ku[j] >> 16));
    float e0 = b2f((unsigned short)(eu[j] & 0xffffu)), e1 = b2f((unsigned short)(eu[j] >> 16));
    s += q0 * (k0 + e0) + q1 * (k1 + e1);
  }
  return s;
}

// one thread per (edge, head): ex = exp(alpha), denom += ex
__global__ void __launch_bounds__(256) k_alpha(const int* __restrict__ ei,
    const unsigned short* __restrict__ qb, const unsigned short* __restrict__ kb,
    const unsigned short* __restrict__ eb, float* __restrict__ ex,
    float* __restrict__ den) {
  int t = blockIdx.x * 256 + threadIdx.x;
  if (t >= NE * 8) return;
  int eid = t >> 3, h = t & 7;
  int src = ei[eid], dst = ei[NE + eid];
  const uint4* qp = (const uint4*)(qb + (size_t)dst*128 + h*16);
  const uint4* kp = (const uint4*)(kb + (size_t)src*128 + h*16);
  const uint4* ep = (const uint4*)(eb + (size_t)eid*128 + h*16);
  float s = dot8(qp[0], kp[0], ep[0]) + dot8(qp[1], kp[1], ep[1]);
  float evv = __expf(s * 0.25f);
  ex[t] = evv;
  unsafeAtomicAdd(&den[(size_t)dst*8 + h], evv);
}

// one thread per (edge, head): att[dst] += a * (v[src] + e)
__global__ void __launch_bounds__(256) k_msg(const int* __restrict__ ei,
    const unsigned short* __restrict__ vb, const unsigned short* __restrict__ eb,
    const float* __restrict__ ex, const float* __restrict__ den,
    float* __restrict__ att) {
  int t = blockIdx.x * 256 + threadIdx.x;
  if (t >= NE * 8) return;
  int eid = t >> 3, h = t & 7;
  int src = ei[eid], dst = ei[NE + eid];
  float a = ex[t] / den[(size_t)dst*8 + h];
  const uint4* vp = (const uint4*)(vb + (size_t)src*128 + h*16);
  const uint4* ep = (const uint4*)(eb + (size_t)eid*128 + h*16);
  float* ap = att + (size_t)dst*128 + h*16;
  #pragma unroll
  for (int half = 0; half < 2; ++half) {
    uint4 vv = vp[half], ee = ep[half];
    const unsigned int* vu = (const unsigned int*)&vv;
    const unsigned int* eu = (const unsigned int*)&ee;
    #pragma unroll
    for (int j = 0; j < 4; ++j) {
      float m0 = a * (b2f((unsigned short)(vu[j] & 0xffffu)) + b2f((unsigned short)(eu[j] & 0xffffu)));
      float m1 = a * (b2f((unsigned short)(vu[j] >> 16))     + b2f((unsigned short)(eu[j] >> 16)));
      unsafeAtomicAdd(ap + half*8 + 2*j,     m0);
      unsafeAtomicAdd(ap + half*8 + 2*j + 1, m1);
    }
  }
}

// beta-gate + LayerNorm + residual ReLU; one wave per node
__global__ void __launch_bounds__(256) k_final(const float* __restrict__ x,
    const float* __restrict__ att, const float* __restrict__ xr,
    const float* __restrict__ Wb, const float* __restrict__ ln_g,
    const float* __restrict__ ln_b, float* __restrict__ out) {
  int wid = threadIdx.x >> 6, lane = threadIdx.x & 63;
  int n = blockIdx.x * 4 + wid;
  if (n >= NN) return;
  int c = lane * 2;
  float2 o = *(const float2*)(att + (size_t)n*128 + c);
  float2 r = *(const float2*)(xr + (size_t)n*128 + c);
  float p = o.x*Wb[c] + o.y*Wb[c+1] + r.x*Wb[128+c] + r.y*Wb[128+c+1]
          + (o.x-r.x)*Wb[256+c] + (o.y-r.y)*Wb[256+c+1];
  #pragma unroll
  for (int off = 32; off > 0; off >>= 1) p += __shfl_xor(p, off);
  float beta = 1.f / (1.f + __expf(-p));
  float g0 = beta*r.x + (1.f-beta)*o.x;
  float g1 = beta*r.y + (1.f-beta)*o.y;
  float m = g0 + g1;
  #pragma unroll
  for (int off = 32; off > 0; off >>= 1) m += __shfl_xor(m, off);
  m *= (1.f/128.f);
  float d0 = g0 - m, d1 = g1 - m;
  float vv = d0*d0 + d1*d1;
  #pragma unroll
  for (int off = 32; off > 0; off >>= 1) vv += __shfl_xor(vv, off);
  vv *= (1.f/128.f);
  float rs = rsqrtf(vv + 1e-5f);
  float n0 = d0*rs*ln_g[c]   + ln_b[c];
  float n1 = d1*rs*ln_g[c+1] + ln_b[c+1];
  float2 xv = *(const float2*)(x + (size_t)n*128 + c);
  float2 res;
  res.x = xv.x + fmaxf(n0, 0.f);
  res.y = xv.y + fmaxf(n1, 0.f);
  *(float2*)(out + (size_t)n*128 + c) = res;
}

extern "C" void kernel_launch(void* const* d_in, const int* in_sizes, int n_in,
                              void* d_out, int out_size, void* d_ws, size_t ws_size,
                              hipStream_t stream) {
  const float* node   = (const float*)d_in[0];
  const int*   ei     = (const int*)  d_in[1];
  const float* es     = (const float*)d_in[2];
  const float* W_edge = (const float*)d_in[3];
  const float* b_edge = (const float*)d_in[4];
  const float* Wq     = (const float*)d_in[5];
  const float* bq     = (const float*)d_in[6];
  const float* Wk     = (const float*)d_in[7];
  const float* bk     = (const float*)d_in[8];
  const float* Wv     = (const float*)d_in[9];
  const float* bv     = (const float*)d_in[10];
  const float* We     = (const float*)d_in[11];
  const float* Wskip  = (const float*)d_in[12];
  const float* bskip  = (const float*)d_in[13];
  const float* Wbeta  = (const float*)d_in[14];
  const float* ln_g   = (const float*)d_in[15];
  const float* ln_b   = (const float*)d_in[16];

  char* ws = (char*)d_ws;
  unsigned short* wce = (unsigned short*)(ws + WS_WCE);
  float*          bce = (float*)(ws + WS_BCE);
  unsigned short* qb  = (unsigned short*)(ws + WS_QB);
  unsigned short* kb  = (unsigned short*)(ws + WS_KB);
  unsigned short* vb  = (unsigned short*)(ws + WS_VB);
  float*          xr  = (float*)(ws + WS_XR);
  unsigned short* eb  = (unsigned short*)(ws + WS_EB);
  float*          ex  = (float*)(ws + WS_EX);
  float*          den = (float*)(ws + WS_DEN);
  float*          att = (float*)(ws + WS_ATT);

  hipMemsetAsync(den, 0, (size_t)NN*8*4,   stream);
  hipMemsetAsync(att, 0, (size_t)NN*128*4, stream);

  k_prep<<<64, 128, 0, stream>>>(W_edge, b_edge, We, wce, bce);
  k_node_lin<<<(NN + 31)/32, 256, 0, stream>>>(node, Wq,bq, Wk,bk, Wv,bv, Wskip,bskip,
                                               qb, kb, vb, xr);
  k_egemm<<<(NE + 127)/128, 256, 0, stream>>>(es, wce, bce, eb);
  k_alpha<<<(NE*8 + 255)/256, 256, 0, stream>>>(ei, qb, kb, eb, ex, den);
  k_msg<<<(NE*8 + 255)/256, 256, 0, stream>>>(ei, vb, eb, ex, den, att);
  k_final<<<(NN + 3)/4, 256, 0, stream>>>(node, att, xr, Wbeta, ln_g, ln_b, (float*)d_out);
}

// Round 2
// 797.605 us; speedup vs baseline: 7.9773x; 7.9773x over previous
//
#include <hip/hip_runtime.h>
#include <cstdint>
#include <cstddef>

#define NN 50000
#define NE 800000
// DN=128, DE=64, H=8, C=16

__device__ __forceinline__ float b2f(unsigned short s) {
  union { unsigned int u; float f; } x; x.u = ((unsigned int)s) << 16; return x.f;
}
__device__ __forceinline__ unsigned short f2b(float f) {
  union { float f; unsigned int u; } x; x.f = f;
  unsigned int r = x.u + 0x7FFFu + ((x.u >> 16) & 1u);
  return (unsigned short)(r >> 16);
}

// ---------------- ws layout (bytes) ----------------
#define WS_WCE   0u           // bf16 [64][128]
#define WS_BCE   32768u       // f32  [128]
#define WS_QB    65536u       // bf16 [NN][128]
#define WS_KB    12865536u    // bf16 [NN][128]
#define WS_VB    25665536u    // bf16 [NN][128]
#define WS_XR    38465536u    // f32  [NN][128]
#define WS_EB    64065536u    // bf16 [NE][128]
#define WS_CNT   268865536u   // int [NN]
#define WS_OFF   269065536u   // int [NN]
#define WS_CUR   269265536u   // int [NN]
#define WS_BSUM  269465536u   // int [256]
#define WS_EIDS  269469632u   // int [NE]
// total = 272,669,632 B

// W_ce = W_edge @ We  (64x128, bf16), b_ce = b_edge @ We (f32)
__global__ void k_prep(const float* __restrict__ W_edge, const float* __restrict__ b_edge,
                       const float* __restrict__ We, unsigned short* __restrict__ wce,
                       float* __restrict__ bce) {
  int i = blockIdx.x;       // 0..63
  int j = threadIdx.x;      // 0..127
  float s = 0.f;
  for (int m = 0; m < 64; ++m) s += W_edge[i*64+m] * We[m*128+j];
  wce[i*128+j] = f2b(s);
  if (i == 0) {
    float bb = 0.f;
    for (int m = 0; m < 64; ++m) bb += b_edge[m] * We[m*128+j];
    bce[j] = bb;
  }
}

// q,k,v (bf16) and x_r (f32): 32 nodes per block, 256 threads
__global__ void __launch_bounds__(256) k_node_lin(const float* __restrict__ x,
    const float* __restrict__ Wq, const float* __restrict__ bq,
    const float* __restrict__ Wk, const float* __restrict__ bk,
    const float* __restrict__ Wv, const float* __restrict__ bv,
    const float* __restrict__ Ws, const float* __restrict__ bs,
    unsigned short* __restrict__ q, unsigned short* __restrict__ k,
    unsigned short* __restrict__ v, float* __restrict__ xr) {
  __shared__ float xs[32][128];
  int n0 = blockIdx.x * 32;
  for (int idx = threadIdx.x; idx < 32*128; idx += 256) {
    int n = idx >> 7, c = idx & 127;
    xs[n][c] = (n0 + n < NN) ? x[(size_t)(n0+n)*128 + c] : 0.f;
  }
  __syncthreads();
  for (int p = 0; p < 2; ++p) {
    int pc = threadIdx.x + p*256;   // 0..511
    int mat = pc >> 7;              // 0..3
    int c = pc & 127;
    const float* W = (mat==0) ? Wq : (mat==1) ? Wk : (mat==2) ? Wv : Ws;
    const float* b = (mat==0) ? bq : (mat==1) ? bk : (mat==2) ? bv : bs;
    float acc[32];
    #pragma unroll
    for (int n = 0; n < 32; ++n) acc[n] = 0.f;
    for (int kk = 0; kk < 128; ++kk) {
      float w = W[kk*128 + c];
      #pragma unroll
      for (int n = 0; n < 32; ++n) acc[n] += xs[n][kk] * w;
    }
    float bias = b[c];
    for (int n = 0; n < 32; ++n) {
      int gn = n0 + n;
      if (gn < NN) {
        float val = acc[n] + bias;
        size_t o = (size_t)gn*128 + c;
        if (mat == 0)      q[o] = f2b(val);
        else if (mat == 1) k[o] = f2b(val);
        else if (mat == 2) v[o] = f2b(val);
        else               xr[o] = val;
      }
    }
  }
}

// e = edge_state @ W_ce + b_ce -> bf16 [NE][128]; 128-edge tile, 8x8 reg tile
__global__ void __launch_bounds__(256) k_egemm(const float* __restrict__ es,
    const unsigned short* __restrict__ wce, const float* __restrict__ bce,
    unsigned short* __restrict__ eb) {
  __shared__ float s_es[128][65];
  __shared__ unsigned short s_w[64][128];
  int e0 = blockIdx.x * 128;
  {
    const unsigned int* w32 = (const unsigned int*)wce;
    unsigned int* sw32 = (unsigned int*)s_w;
    for (int idx = threadIdx.x; idx < 4096; idx += 256) sw32[idx] = w32[idx];
  }
  for (int idx = threadIdx.x; idx < 128*64; idx += 256) {
    int r = idx >> 6, c = idx & 63;
    int ge = e0 + r;
    s_es[r][c] = (ge < NE) ? es[(size_t)ge*64 + c] : 0.f;
  }
  __syncthreads();
  int tr = threadIdx.x >> 4, tc = threadIdx.x & 15;
  int er0 = tr * 8, c0 = tc * 8;
  float acc[8][8];
  #pragma unroll
  for (int i = 0; i < 8; ++i)
    #pragma unroll
    for (int j = 0; j < 8; ++j) acc[i][j] = 0.f;
  for (int kk = 0; kk < 64; ++kk) {
    float wv[8];
    uint4 wq = *(const uint4*)&s_w[kk][c0];
    const unsigned int* wu = (const unsigned int*)&wq;
    #pragma unroll
    for (int j = 0; j < 4; ++j) {
      wv[2*j]   = b2f((unsigned short)(wu[j] & 0xffffu));
      wv[2*j+1] = b2f((unsigned short)(wu[j] >> 16));
    }
    float ev[8];
    #pragma unroll
    for (int i = 0; i < 8; ++i) ev[i] = s_es[er0+i][kk];
    #pragma unroll
    for (int i = 0; i < 8; ++i)
      #pragma unroll
      for (int j = 0; j < 8; ++j) acc[i][j] += ev[i] * wv[j];
  }
  #pragma unroll
  for (int i = 0; i < 8; ++i) {
    int ge = e0 + er0 + i;
    if (ge < NE) {
      unsigned short o[8];
      #pragma unroll
      for (int j = 0; j < 8; ++j) o[j] = f2b(acc[i][j] + bce[c0+j]);
      *(uint4*)&eb[(size_t)ge*128 + c0] = *(const uint4*)o;
    }
  }
}

// -------- CSR build --------
__global__ void __launch_bounds__(256) k_hist(const int* __restrict__ ei, int* __restrict__ cnt) {
  int t = blockIdx.x * 256 + threadIdx.x;
  if (t < NE) atomicAdd(&cnt[ei[NE + t]], 1);
}

// block-level exclusive scan, 256 per block
__global__ void __launch_bounds__(256) k_scanA(const int* __restrict__ cnt,
    int* __restrict__ off, int* __restrict__ bsum) {
  __shared__ int s[256];
  int i = blockIdx.x * 256 + threadIdx.x;
  int v = (i < NN) ? cnt[i] : 0;
  s[threadIdx.x] = v;
  __syncthreads();
  #pragma unroll
  for (int d = 1; d < 256; d <<= 1) {
    int t = (threadIdx.x >= d) ? s[threadIdx.x - d] : 0;
    __syncthreads();
    s[threadIdx.x] += t;
    __syncthreads();
  }
  if (i < NN) off[i] = s[threadIdx.x] - v;
  if (threadIdx.x == 255) bsum[blockIdx.x] = s[255];
}

__global__ void __launch_bounds__(256) k_scanB(int* __restrict__ bsum, int nb) {
  __shared__ int s[256];
  int v = (threadIdx.x < nb) ? bsum[threadIdx.x] : 0;
  s[threadIdx.x] = v;
  __syncthreads();
  #pragma unroll
  for (int d = 1; d < 256; d <<= 1) {
    int t = (threadIdx.x >= d) ? s[threadIdx.x - d] : 0;
    __syncthreads();
    s[threadIdx.x] += t;
    __syncthreads();
  }
  if (threadIdx.x < nb) bsum[threadIdx.x] = s[threadIdx.x] - v;
}

__global__ void __launch_bounds__(256) k_scanC(int* __restrict__ off,
    const int* __restrict__ bsum, int* __restrict__ cur) {
  int i = blockIdx.x * 256 + threadIdx.x;
  if (i < NN) {
    int o = off[i] + bsum[blockIdx.x];
    off[i] = o;
    cur[i] = o;
  }
}

__global__ void __launch_bounds__(256) k_scatter(const int* __restrict__ ei,
    int* __restrict__ cur, int* __restrict__ eids) {
  int t = blockIdx.x * 256 + threadIdx.x;
  if (t < NE) {
    int d = ei[NE + t];
    int p = atomicAdd(&cur[d], 1);
    eids[p] = t;
  }
}

// -------- fused attention gather + beta-gate + LN + residual ReLU --------
// one wave per node; lane l owns channels 2l, 2l+1; head = l>>3
__global__ void __launch_bounds__(256) k_attn(const int* __restrict__ ei,
    const int* __restrict__ off, const int* __restrict__ cnt,
    const int* __restrict__ eids,
    const unsigned short* __restrict__ qb, const unsigned short* __restrict__ kb,
    const unsigned short* __restrict__ vb, const unsigned short* __restrict__ eb,
    const float* __restrict__ xr, const float* __restrict__ x,
    const float* __restrict__ Wb, const float* __restrict__ ln_g,
    const float* __restrict__ ln_b, float* __restrict__ out) {
  int wid = threadIdx.x >> 6, lane = threadIdx.x & 63;
  int n = blockIdx.x * 4 + wid;
  if (n >= NN) return;
  int c = lane * 2;

  unsigned int qu = *(const unsigned int*)(qb + (size_t)n*128 + c);
  float q0 = b2f((unsigned short)(qu & 0xffffu)), q1 = b2f((unsigned short)(qu >> 16));

  int start = off[n], m = cnt[n];
  float acc0 = 0.f, acc1 = 0.f, den = 0.f;
  for (int i = 0; i < m; ++i) {
    int e = eids[start + i];
    int src = ei[e];
    unsigned int ku = *(const unsigned int*)(kb + (size_t)src*128 + c);
    unsigned int eu = *(const unsigned int*)(eb + (size_t)e*128 + c);
    unsigned int vu = *(const unsigned int*)(vb + (size_t)src*128 + c);
    float e0 = b2f((unsigned short)(eu & 0xffffu)), e1 = b2f((unsigned short)(eu >> 16));
    float p = q0*(b2f((unsigned short)(ku & 0xffffu)) + e0)
            + q1*(b2f((unsigned short)(ku >> 16)) + e1);
    p += __shfl_xor(p, 1);
    p += __shfl_xor(p, 2);
    p += __shfl_xor(p, 4);
    float a = __expf(p * 0.25f);
    den  += a;
    acc0 += a * (b2f((unsigned short)(vu & 0xffffu)) + e0);
    acc1 += a * (b2f((unsigned short)(vu >> 16)) + e1);
  }
  float inv = (m > 0) ? 1.f / den : 0.f;
  float o0 = acc0 * inv, o1 = acc1 * inv;

  // epilogue
  float2 r = *(const float2*)(xr + (size_t)n*128 + c);
  float p = o0*Wb[c] + o1*Wb[c+1] + r.x*Wb[128+c] + r.y*Wb[128+c+1]
          + (o0-r.x)*Wb[256+c] + (o1-r.y)*Wb[256+c+1];
  #pragma unroll
  for (int offs = 32; offs > 0; offs >>= 1) p += __shfl_xor(p, offs);
  float beta = 1.f / (1.f + __expf(-p));
  float g0 = beta*r.x + (1.f-beta)*o0;
  float g1 = beta*r.y + (1.f-beta)*o1;
  float msum = g0 + g1;
  #pragma unroll
  for (int offs = 32; offs > 0; offs >>= 1) msum += __shfl_xor(msum, offs);
  msum *= (1.f/128.f);
  float d0 = g0 - msum, d1 = g1 - msum;
  float vv = d0*d0 + d1*d1;
  #pragma unroll
  for (int offs = 32; offs > 0; offs >>= 1) vv += __shfl_xor(vv, offs);
  vv *= (1.f/128.f);
  float rs = rsqrtf(vv + 1e-5f);
  float n0 = d0*rs*ln_g[c]   + ln_b[c];
  float n1 = d1*rs*ln_g[c+1] + ln_b[c+1];
  float2 xv = *(const float2*)(x + (size_t)n*128 + c);
  float2 res;
  res.x = xv.x + fmaxf(n0, 0.f);
  res.y = xv.y + fmaxf(n1, 0.f);
  *(float2*)(out + (size_t)n*128 + c) = res;
}

extern "C" void kernel_launch(void* const* d_in, const int* in_sizes, int n_in,
                              void* d_out, int out_size, void* d_ws, size_t ws_size,
                              hipStream_t stream) {
  const float* node   = (const float*)d_in[0];
  const int*   ei     = (const int*)  d_in[1];
  const float* es     = (const float*)d_in[2];
  const float* W_edge = (const float*)d_in[3];
  const float* b_edge = (const float*)d_in[4];
  const float* Wq     = (const float*)d_in[5];
  const float* bq     = (const float*)d_in[6];
  const float* Wk     = (const float*)d_in[7];
  const float* bk     = (const float*)d_in[8];
  const float* Wv     = (const float*)d_in[9];
  const float* bv     = (const float*)d_in[10];
  const float* We     = (const float*)d_in[11];
  const float* Wskip  = (const float*)d_in[12];
  const float* bskip  = (const float*)d_in[13];
  const float* Wbeta  = (const float*)d_in[14];
  const float* ln_g   = (const float*)d_in[15];
  const float* ln_b   = (const float*)d_in[16];

  char* ws = (char*)d_ws;
  unsigned short* wce = (unsigned short*)(ws + WS_WCE);
  float*          bce = (float*)(ws + WS_BCE);
  unsigned short* qb  = (unsigned short*)(ws + WS_QB);
  unsigned short* kb  = (unsigned short*)(ws + WS_KB);
  unsigned short* vb  = (unsigned short*)(ws + WS_VB);
  float*          xr  = (float*)(ws + WS_XR);
  unsigned short* eb  = (unsigned short*)(ws + WS_EB);
  int*            cnt = (int*)(ws + WS_CNT);
  int*            off = (int*)(ws + WS_OFF);
  int*            cur = (int*)(ws + WS_CUR);
  int*            bsm = (int*)(ws + WS_BSUM);
  int*            eids= (int*)(ws + WS_EIDS);

  hipMemsetAsync(cnt, 0, (size_t)NN*4, stream);

  k_prep<<<64, 128, 0, stream>>>(W_edge, b_edge, We, wce, bce);
  k_node_lin<<<(NN + 31)/32, 256, 0, stream>>>(node, Wq,bq, Wk,bk, Wv,bv, Wskip,bskip,
                                               qb, kb, vb, xr);
  k_egemm<<<(NE + 127)/128, 256, 0, stream>>>(es, wce, bce, eb);

  const int nbScan = (NN + 255)/256;  // 196
  k_hist<<<(NE + 255)/256, 256, 0, stream>>>(ei, cnt);
  k_scanA<<<nbScan, 256, 0, stream>>>(cnt, off, bsm);
  k_scanB<<<1, 256, 0, stream>>>(bsm, nbScan);
  k_scanC<<<nbScan, 256, 0, stream>>>(off, bsm, cur);
  k_scatter<<<(NE + 255)/256, 256, 0, stream>>>(ei, cur, eids);

  k_attn<<<(NN + 3)/4, 256, 0, stream>>>(ei, off, cnt, eids, qb, kb, vb, eb,
                                         xr, node, Wbeta, ln_g, ln_b, (float*)d_out);
}

// Round 3
// 456.775 us; speedup vs baseline: 13.9297x; 1.7462x over previous
//
#include <hip/hip_runtime.h>
#include <cstdint>
#include <cstddef>

#define NN 50000
#define NE 800000
// DN=128, DE=64, H=8, C=16

typedef short bf16x8 __attribute__((ext_vector_type(8)));
typedef float f32x4 __attribute__((ext_vector_type(4)));

__device__ __forceinline__ float b2f(unsigned short s) {
  union { unsigned int u; float f; } x; x.u = ((unsigned int)s) << 16; return x.f;
}
__device__ __forceinline__ unsigned short f2b(float f) {
  union { float f; unsigned int u; } x; x.f = f;
  unsigned int r = x.u + 0x7FFFu + ((x.u >> 16) & 1u);
  return (unsigned short)(r >> 16);
}

// ---------------- ws layout (bytes) ----------------
#define WS_WCE    0u          // bf16 [64][128] (16KB)
#define WS_BCE    16384u      // f32 [128]
#define WS_WCEF   20480u      // bf16 frags 8ct*2s*64l*8j (16KB)
#define WS_WALLF  40960u      // bf16 frags 4m*8ct*4s*64l*8j (128KB)
#define WS_BALL   172032u     // f32 [512]
#define WS_QB     180224u     // bf16 [NN][128]
#define WS_KB     12980224u   // bf16 [NN][128]
#define WS_VB     25780224u   // bf16 [NN][128]
#define WS_XR     38580224u   // f32  [NN][128]
#define WS_EB     64180224u   // bf16 [NE][128]
#define WS_CNT    268980224u  // int [NN]
#define WS_OFF    269180224u  // int [NN]
#define WS_CUR    269380224u  // int [NN]
#define WS_BSUM   269580224u  // int [256]
#define WS_EIDS   269584320u  // int [NE]
// end = 272,784,320 B (round-1 used 321MB OK)

// W_ce = W_edge @ We (64x128, bf16), b_ce = b_edge @ We (f32)
__global__ void k_prep(const float* __restrict__ W_edge, const float* __restrict__ b_edge,
                       const float* __restrict__ We, unsigned short* __restrict__ wce,
                       float* __restrict__ bce) {
  int i = blockIdx.x;       // 0..63
  int j = threadIdx.x;      // 0..127
  float s = 0.f;
  for (int m = 0; m < 64; ++m) s += W_edge[i*64+m] * We[m*128+j];
  wce[i*128+j] = f2b(s);
  if (i == 0) {
    float bb = 0.f;
    for (int m = 0; m < 64; ++m) bb += b_edge[m] * We[m*128+j];
    bce[j] = bb;
  }
}

// pack wce [64][128] into A-frag layout: frag(ct,s): lane l elem j = W[s*32+(l>>4)*8+j][ct*16+(l&15)]
__global__ void k_pack_wce(const unsigned short* __restrict__ wce, unsigned short* __restrict__ wcef) {
  int fb = blockIdx.x;           // 0..15
  int ct = fb >> 1, s = fb & 1;
  int l = threadIdx.x;           // 0..63
  unsigned short* dst = wcef + (((size_t)(ct*2+s))*64 + l)*8;
  int col = ct*16 + (l & 15);
  int k0 = s*32 + (l >> 4)*8;
  #pragma unroll
  for (int j = 0; j < 8; ++j) dst[j] = wce[(k0+j)*128 + col];
}

// pack Wq/Wk/Wv/Wskip (fp32 [128][128], y=x@W layout) into bf16 A-frags
__global__ void k_pack_wall(const float* __restrict__ Wq, const float* __restrict__ Wk,
                            const float* __restrict__ Wv, const float* __restrict__ Ws,
                            unsigned short* __restrict__ wallf) {
  int fb = blockIdx.x;           // 0..127
  int mat = fb >> 5, ct = (fb >> 2) & 7, s = fb & 3;
  int l = threadIdx.x;
  const float* W = (mat==0) ? Wq : (mat==1) ? Wk : (mat==2) ? Wv : Ws;
  unsigned short* dst = wallf + ((((size_t)(mat*8+ct))*4 + s)*64 + l)*8;
  int col = ct*16 + (l & 15);
  int k0 = s*32 + (l >> 4)*8;
  #pragma unroll
  for (int j = 0; j < 8; ++j) dst[j] = f2b(W[(k0+j)*128 + col]);
}

__global__ void k_pack_bias(const float* __restrict__ bq, const float* __restrict__ bk,
                            const float* __restrict__ bv, const float* __restrict__ bs,
                            float* __restrict__ ball) {
  int m = blockIdx.x, c = threadIdx.x;
  const float* b = (m==0) ? bq : (m==1) ? bk : (m==2) ? bv : bs;
  ball[m*128 + c] = b[c];
}

// node linears via MFMA: grid = n_tiles*4, block 256 (4 waves)
// blockIdx: mat = b&3, nt = b>>2. Output 128 nodes x 128 cols of matrix `mat`.
__global__ void __launch_bounds__(256) k_node_mfma(const float* __restrict__ x,
    const unsigned short* __restrict__ wallf, const float* __restrict__ ball,
    unsigned short* __restrict__ qb, unsigned short* __restrict__ kb,
    unsigned short* __restrict__ vb, float* __restrict__ xr) {
  __shared__ unsigned short sA[128*128];   // 32KB, chunk-swizzled bf16
  int mat = blockIdx.x & 3;
  int n0 = (blockIdx.x >> 2) * 128;
  // stage x tile -> bf16 LDS (16 chunks of 16B per row)
  for (int i = 0; i < 8; ++i) {
    int c = threadIdx.x + i*256;       // 0..2047
    int row = c >> 4, ch = c & 15;
    int sw = (ch & 8) | ((ch & 7) ^ (row & 7));
    unsigned short tmp[8];
    if (n0 + row < NN) {
      const float* src = x + (size_t)(n0+row)*128 + ch*8;
      float4 f0 = *(const float4*)src;
      float4 f1 = *(const float4*)(src + 4);
      tmp[0]=f2b(f0.x); tmp[1]=f2b(f0.y); tmp[2]=f2b(f0.z); tmp[3]=f2b(f0.w);
      tmp[4]=f2b(f1.x); tmp[5]=f2b(f1.y); tmp[6]=f2b(f1.z); tmp[7]=f2b(f1.w);
    } else {
      #pragma unroll
      for (int j = 0; j < 8; ++j) tmp[j] = 0;
    }
    *(uint4*)&sA[row*128 + sw*8] = *(const uint4*)tmp;
  }
  __syncthreads();
  int l = threadIdx.x & 63, w = threadIdx.x >> 6;
  int g = l >> 4, ln = l & 15;
  f32x4 acc[2][8];
  #pragma unroll
  for (int rt = 0; rt < 2; ++rt)
    #pragma unroll
    for (int ct = 0; ct < 8; ++ct) acc[rt][ct] = (f32x4){0.f,0.f,0.f,0.f};
  for (int s = 0; s < 4; ++s) {
    bf16x8 wf[8];
    #pragma unroll
    for (int ct = 0; ct < 8; ++ct)
      wf[ct] = *(const bf16x8*)(wallf + ((((size_t)(mat*8+ct))*4 + s)*64 + l)*8);
    bf16x8 bfr[2];
    #pragma unroll
    for (int rt = 0; rt < 2; ++rt) {
      int row = w*32 + rt*16 + ln;
      int ch = s*4 + g;
      int sw = (ch & 8) | ((ch & 7) ^ (row & 7));
      bfr[rt] = *(const bf16x8*)&sA[row*128 + sw*8];
    }
    #pragma unroll
    for (int rt = 0; rt < 2; ++rt)
      #pragma unroll
      for (int ct = 0; ct < 8; ++ct)
        acc[rt][ct] = __builtin_amdgcn_mfma_f32_16x16x32_bf16(wf[ct], bfr[rt], acc[rt][ct], 0, 0, 0);
  }
  // epilogue: lane holds cols ct*16+g*4..+3 of node row (l&15) per rt
  #pragma unroll
  for (int rt = 0; rt < 2; ++rt) {
    int node = n0 + w*32 + rt*16 + ln;
    if (node >= NN) continue;
    #pragma unroll
    for (int ct = 0; ct < 8; ++ct) {
      int c0 = ct*16 + g*4;
      float4 bi = *(const float4*)(ball + mat*128 + c0);
      float v0 = acc[rt][ct][0] + bi.x, v1 = acc[rt][ct][1] + bi.y;
      float v2 = acc[rt][ct][2] + bi.z, v3 = acc[rt][ct][3] + bi.w;
      if (mat == 3) {
        float4 o = {v0, v1, v2, v3};
        *(float4*)(xr + (size_t)node*128 + c0) = o;
      } else {
        unsigned short* dst = (mat==0) ? qb : (mat==1) ? kb : vb;
        unsigned short o[4] = {f2b(v0), f2b(v1), f2b(v2), f2b(v3)};
        *(uint2*)(dst + (size_t)node*128 + c0) = *(const uint2*)o;
      }
    }
  }
}

// edge GEMM via MFMA: e = es @ W_ce + b_ce -> bf16 [NE][128]; 128 edges/block
__global__ void __launch_bounds__(256) k_egemm_mfma(const float* __restrict__ es,
    const unsigned short* __restrict__ wcef, const float* __restrict__ bce,
    unsigned short* __restrict__ eb) {
  __shared__ unsigned short sA[128*64];    // 16KB, chunk-swizzled bf16
  int e0 = blockIdx.x * 128;
  for (int i = 0; i < 4; ++i) {
    int c = threadIdx.x + i*256;       // 0..1023
    int row = c >> 3, ch = c & 7;
    int sw = ch ^ (row & 7);
    const float* src = es + (size_t)(e0+row)*64 + ch*8;
    float4 f0 = *(const float4*)src;
    float4 f1 = *(const float4*)(src + 4);
    unsigned short tmp[8];
    tmp[0]=f2b(f0.x); tmp[1]=f2b(f0.y); tmp[2]=f2b(f0.z); tmp[3]=f2b(f0.w);
    tmp[4]=f2b(f1.x); tmp[5]=f2b(f1.y); tmp[6]=f2b(f1.z); tmp[7]=f2b(f1.w);
    *(uint4*)&sA[row*64 + sw*8] = *(const uint4*)tmp;
  }
  __syncthreads();
  int l = threadIdx.x & 63, w = threadIdx.x >> 6;
  int g = l >> 4, ln = l & 15;
  f32x4 acc[2][8];
  #pragma unroll
  for (int rt = 0; rt < 2; ++rt)
    #pragma unroll
    for (int ct = 0; ct < 8; ++ct) acc[rt][ct] = (f32x4){0.f,0.f,0.f,0.f};
  #pragma unroll
  for (int s = 0; s < 2; ++s) {
    bf16x8 wf[8];
    #pragma unroll
    for (int ct = 0; ct < 8; ++ct)
      wf[ct] = *(const bf16x8*)(wcef + (((size_t)(ct*2+s))*64 + l)*8);
    bf16x8 bfr[2];
    #pragma unroll
    for (int rt = 0; rt < 2; ++rt) {
      int row = w*32 + rt*16 + ln;
      int ch = (s*4 + g) ^ (row & 7);
      bfr[rt] = *(const bf16x8*)&sA[row*64 + ch*8];
    }
    #pragma unroll
    for (int rt = 0; rt < 2; ++rt)
      #pragma unroll
      for (int ct = 0; ct < 8; ++ct)
        acc[rt][ct] = __builtin_amdgcn_mfma_f32_16x16x32_bf16(wf[ct], bfr[rt], acc[rt][ct], 0, 0, 0);
  }
  #pragma unroll
  for (int rt = 0; rt < 2; ++rt) {
    int edge = e0 + w*32 + rt*16 + ln;
    unsigned short* dst = eb + (size_t)edge*128;
    #pragma unroll
    for (int ct = 0; ct < 8; ++ct) {
      int c0 = ct*16 + g*4;
      float4 bi = *(const float4*)(bce + c0);
      unsigned short o[4] = {f2b(acc[rt][ct][0]+bi.x), f2b(acc[rt][ct][1]+bi.y),
                             f2b(acc[rt][ct][2]+bi.z), f2b(acc[rt][ct][3]+bi.w)};
      *(uint2*)(dst + c0) = *(const uint2*)o;
    }
  }
}

// -------- CSR build --------
__global__ void __launch_bounds__(256) k_hist(const int* __restrict__ ei, int* __restrict__ cnt) {
  int t = blockIdx.x * 256 + threadIdx.x;
  if (t < NE) atomicAdd(&cnt[ei[NE + t]], 1);
}

__global__ void __launch_bounds__(256) k_scanA(const int* __restrict__ cnt,
    int* __restrict__ off, int* __restrict__ bsum) {
  __shared__ int s[256];
  int i = blockIdx.x * 256 + threadIdx.x;
  int v = (i < NN) ? cnt[i] : 0;
  s[threadIdx.x] = v;
  __syncthreads();
  #pragma unroll
  for (int d = 1; d < 256; d <<= 1) {
    int t = (threadIdx.x >= d) ? s[threadIdx.x - d] : 0;
    __syncthreads();
    s[threadIdx.x] += t;
    __syncthreads();
  }
  if (i < NN) off[i] = s[threadIdx.x] - v;
  if (threadIdx.x == 255) bsum[blockIdx.x] = s[255];
}

__global__ void __launch_bounds__(256) k_scanB(int* __restrict__ bsum, int nb) {
  __shared__ int s[256];
  int v = (threadIdx.x < nb) ? bsum[threadIdx.x] : 0;
  s[threadIdx.x] = v;
  __syncthreads();
  #pragma unroll
  for (int d = 1; d < 256; d <<= 1) {
    int t = (threadIdx.x >= d) ? s[threadIdx.x - d] : 0;
    __syncthreads();
    s[threadIdx.x] += t;
    __syncthreads();
  }
  if (threadIdx.x < nb) bsum[threadIdx.x] = s[threadIdx.x] - v;
}

__global__ void __launch_bounds__(256) k_scanC(int* __restrict__ off,
    const int* __restrict__ bsum, int* __restrict__ cur) {
  int i = blockIdx.x * 256 + threadIdx.x;
  if (i < NN) {
    int o = off[i] + bsum[blockIdx.x];
    off[i] = o;
    cur[i] = o;
  }
}

__global__ void __launch_bounds__(256) k_scatter(const int* __restrict__ ei,
    int* __restrict__ cur, int* __restrict__ eids) {
  int t = blockIdx.x * 256 + threadIdx.x;
  if (t < NE) {
    int d = ei[NE + t];
    int p = atomicAdd(&cur[d], 1);
    eids[p] = t;
  }
}

// -------- fused attention gather + beta-gate + LN + residual ReLU --------
__global__ void __launch_bounds__(256) k_attn(const int* __restrict__ ei,
    const int* __restrict__ off, const int* __restrict__ cnt,
    const int* __restrict__ eids,
    const unsigned short* __restrict__ qb, const unsigned short* __restrict__ kb,
    const unsigned short* __restrict__ vb, const unsigned short* __restrict__ eb,
    const float* __restrict__ xr, const float* __restrict__ x,
    const float* __restrict__ Wb, const float* __restrict__ ln_g,
    const float* __restrict__ ln_b, float* __restrict__ out) {
  int wid = threadIdx.x >> 6, lane = threadIdx.x & 63;
  int n = blockIdx.x * 4 + wid;
  if (n >= NN) return;
  int c = lane * 2;

  unsigned int qu = *(const unsigned int*)(qb + (size_t)n*128 + c);
  float q0 = b2f((unsigned short)(qu & 0xffffu)), q1 = b2f((unsigned short)(qu >> 16));

  int start = off[n], m = cnt[n];
  float acc0 = 0.f, acc1 = 0.f, den = 0.f;
  for (int i = 0; i < m; ++i) {
    int e = eids[start + i];
    int src = ei[e];
    unsigned int ku = *(const unsigned int*)(kb + (size_t)src*128 + c);
    unsigned int eu = *(const unsigned int*)(eb + (size_t)e*128 + c);
    unsigned int vu = *(const unsigned int*)(vb + (size_t)src*128 + c);
    float e0 = b2f((unsigned short)(eu & 0xffffu)), e1 = b2f((unsigned short)(eu >> 16));
    float p = q0*(b2f((unsigned short)(ku & 0xffffu)) + e0)
            + q1*(b2f((unsigned short)(ku >> 16)) + e1);
    p += __shfl_xor(p, 1);
    p += __shfl_xor(p, 2);
    p += __shfl_xor(p, 4);
    float a = __expf(p * 0.25f);
    den  += a;
    acc0 += a * (b2f((unsigned short)(vu & 0xffffu)) + e0);
    acc1 += a * (b2f((unsigned short)(vu >> 16)) + e1);
  }
  float inv = (m > 0) ? 1.f / den : 0.f;
  float o0 = acc0 * inv, o1 = acc1 * inv;

  float2 r = *(const float2*)(xr + (size_t)n*128 + c);
  float p = o0*Wb[c] + o1*Wb[c+1] + r.x*Wb[128+c] + r.y*Wb[128+c+1]
          + (o0-r.x)*Wb[256+c] + (o1-r.y)*Wb[256+c+1];
  #pragma unroll
  for (int offs = 32; offs > 0; offs >>= 1) p += __shfl_xor(p, offs);
  float beta = 1.f / (1.f + __expf(-p));
  float g0 = beta*r.x + (1.f-beta)*o0;
  float g1 = beta*r.y + (1.f-beta)*o1;
  float msum = g0 + g1;
  #pragma unroll
  for (int offs = 32; offs > 0; offs >>= 1) msum += __shfl_xor(msum, offs);
  msum *= (1.f/128.f);
  float d0 = g0 - msum, d1 = g1 - msum;
  float vv = d0*d0 + d1*d1;
  #pragma unroll
  for (int offs = 32; offs > 0; offs >>= 1) vv += __shfl_xor(vv, offs);
  vv *= (1.f/128.f);
  float rs = rsqrtf(vv + 1e-5f);
  float n0 = d0*rs*ln_g[c]   + ln_b[c];
  float n1 = d1*rs*ln_g[c+1] + ln_b[c+1];
  float2 xv = *(const float2*)(x + (size_t)n*128 + c);
  float2 res;
  res.x = xv.x + fmaxf(n0, 0.f);
  res.y = xv.y + fmaxf(n1, 0.f);
  *(float2*)(out + (size_t)n*128 + c) = res;
}

extern "C" void kernel_launch(void* const* d_in, const int* in_sizes, int n_in,
                              void* d_out, int out_size, void* d_ws, size_t ws_size,
                              hipStream_t stream) {
  const float* node   = (const float*)d_in[0];
  const int*   ei     = (const int*)  d_in[1];
  const float* es     = (const float*)d_in[2];
  const float* W_edge = (const float*)d_in[3];
  const float* b_edge = (const float*)d_in[4];
  const float* Wq     = (const float*)d_in[5];
  const float* bq     = (const float*)d_in[6];
  const float* Wk     = (const float*)d_in[7];
  const float* bk     = (const float*)d_in[8];
  const float* Wv     = (const float*)d_in[9];
  const float* bv     = (const float*)d_in[10];
  const float* We     = (const float*)d_in[11];
  const float* Wskip  = (const float*)d_in[12];
  const float* bskip  = (const float*)d_in[13];
  const float* Wbeta  = (const float*)d_in[14];
  const float* ln_g   = (const float*)d_in[15];
  const float* ln_b   = (const float*)d_in[16];

  char* ws = (char*)d_ws;
  unsigned short* wce   = (unsigned short*)(ws + WS_WCE);
  float*          bce   = (float*)(ws + WS_BCE);
  unsigned short* wcef  = (unsigned short*)(ws + WS_WCEF);
  unsigned short* wallf = (unsigned short*)(ws + WS_WALLF);
  float*          ball  = (float*)(ws + WS_BALL);
  unsigned short* qb  = (unsigned short*)(ws + WS_QB);
  unsigned short* kb  = (unsigned short*)(ws + WS_KB);
  unsigned short* vb  = (unsigned short*)(ws + WS_VB);
  float*          xr  = (float*)(ws + WS_XR);
  unsigned short* eb  = (unsigned short*)(ws + WS_EB);
  int*            cnt = (int*)(ws + WS_CNT);
  int*            off = (int*)(ws + WS_OFF);
  int*            cur = (int*)(ws + WS_CUR);
  int*            bsm = (int*)(ws + WS_BSUM);
  int*            eids= (int*)(ws + WS_EIDS);

  hipMemsetAsync(cnt, 0, (size_t)NN*4, stream);

  k_prep<<<64, 128, 0, stream>>>(W_edge, b_edge, We, wce, bce);
  k_pack_wce<<<16, 64, 0, stream>>>(wce, wcef);
  k_pack_wall<<<128, 64, 0, stream>>>(Wq, Wk, Wv, Wskip, wallf);
  k_pack_bias<<<4, 128, 0, stream>>>(bq, bk, bv, bskip, ball);

  const int ntiles = (NN + 127) / 128;  // 391
  k_node_mfma<<<ntiles*4, 256, 0, stream>>>(node, wallf, ball, qb, kb, vb, xr);
  k_egemm_mfma<<<NE/128, 256, 0, stream>>>(es, wcef, bce, eb);

  const int nbScan = (NN + 255)/256;  // 196
  k_hist<<<(NE + 255)/256, 256, 0, stream>>>(ei, cnt);
  k_scanA<<<nbScan, 256, 0, stream>>>(cnt, off, bsm);
  k_scanB<<<1, 256, 0, stream>>>(bsm, nbScan);
  k_scanC<<<nbScan, 256, 0, stream>>>(off, bsm, cur);
  k_scatter<<<(NE + 255)/256, 256, 0, stream>>>(ei, cur, eids);

  k_attn<<<(NN + 3)/4, 256, 0, stream>>>(ei, off, cnt, eids, qb, kb, vb, eb,
                                         xr, node, Wbeta, ln_g, ln_b, (float*)d_out);
}

// Round 4
// 396.939 us; speedup vs baseline: 16.0295x; 1.1507x over previous
//
#include <hip/hip_runtime.h>
#include <cstdint>
#include <cstddef>

#define NN 50000
#define NE 800000
// DN=128, DE=64, H=8, C=16

typedef short bf16x8 __attribute__((ext_vector_type(8)));
typedef float f32x4 __attribute__((ext_vector_type(4)));

__device__ __forceinline__ float b2f(unsigned short s) {
  union { unsigned int u; float f; } x; x.u = ((unsigned int)s) << 16; return x.f;
}
__device__ __forceinline__ unsigned short f2b(float f) {
  union { float f; unsigned int u; } x; x.f = f;
  unsigned int r = x.u + 0x7FFFu + ((x.u >> 16) & 1u);
  return (unsigned short)(r >> 16);
}

// ---------------- ws layout (bytes) ----------------
#define WS_WCE    0u          // bf16 [64][128] (16KB)
#define WS_BCE    16384u      // f32 [128]
#define WS_WCEF   20480u      // bf16 frags 8ct*2s*64l*8j (16KB)
#define WS_WALLF  40960u      // bf16 frags 4m*8ct*4s*64l*8j (128KB)
#define WS_BALL   172032u     // f32 [512]
#define WS_QB     180224u     // bf16 [NN][128]
#define WS_KB     12980224u   // bf16 [NN][128]
#define WS_VB     25780224u   // bf16 [NN][128]
#define WS_XR     38580224u   // f32  [NN][128]
#define WS_EB     64180224u   // bf16 [NE][128] (CSR-sorted rows)
#define WS_CNT    268980224u  // int [NN]
#define WS_OFF    269180224u  // int [NN]
#define WS_CUR    269380224u  // int [NN]
#define WS_BSUM   269580224u  // int [256]
#define WS_POS    269584320u  // int [NE]
#define WS_SRCS   272784320u  // int [NE]
// end = 275,984,320 B

// W_ce = W_edge @ We (64x128, bf16), b_ce = b_edge @ We (f32)
__global__ void k_prep(const float* __restrict__ W_edge, const float* __restrict__ b_edge,
                       const float* __restrict__ We, unsigned short* __restrict__ wce,
                       float* __restrict__ bce) {
  int i = blockIdx.x;       // 0..63
  int j = threadIdx.x;      // 0..127
  float s = 0.f;
  for (int m = 0; m < 64; ++m) s += W_edge[i*64+m] * We[m*128+j];
  wce[i*128+j] = f2b(s);
  if (i == 0) {
    float bb = 0.f;
    for (int m = 0; m < 64; ++m) bb += b_edge[m] * We[m*128+j];
    bce[j] = bb;
  }
}

// pack wce [64][128] into A-frag layout
__global__ void k_pack_wce(const unsigned short* __restrict__ wce, unsigned short* __restrict__ wcef) {
  int fb = blockIdx.x;           // 0..15
  int ct = fb >> 1, s = fb & 1;
  int l = threadIdx.x;           // 0..63
  unsigned short* dst = wcef + (((size_t)(ct*2+s))*64 + l)*8;
  int col = ct*16 + (l & 15);
  int k0 = s*32 + (l >> 4)*8;
  #pragma unroll
  for (int j = 0; j < 8; ++j) dst[j] = wce[(k0+j)*128 + col];
}

// pack Wq/Wk/Wv/Wskip (fp32 [128][128], y=x@W layout) into bf16 A-frags
__global__ void k_pack_wall(const float* __restrict__ Wq, const float* __restrict__ Wk,
                            const float* __restrict__ Wv, const float* __restrict__ Ws,
                            unsigned short* __restrict__ wallf) {
  int fb = blockIdx.x;           // 0..127
  int mat = fb >> 5, ct = (fb >> 2) & 7, s = fb & 3;
  int l = threadIdx.x;
  const float* W = (mat==0) ? Wq : (mat==1) ? Wk : (mat==2) ? Wv : Ws;
  unsigned short* dst = wallf + ((((size_t)(mat*8+ct))*4 + s)*64 + l)*8;
  int col = ct*16 + (l & 15);
  int k0 = s*32 + (l >> 4)*8;
  #pragma unroll
  for (int j = 0; j < 8; ++j) dst[j] = f2b(W[(k0+j)*128 + col]);
}

__global__ void k_pack_bias(const float* __restrict__ bq, const float* __restrict__ bk,
                            const float* __restrict__ bv, const float* __restrict__ bs,
                            float* __restrict__ ball) {
  int m = blockIdx.x, c = threadIdx.x;
  const float* b = (m==0) ? bq : (m==1) ? bk : (m==2) ? bv : bs;
  ball[m*128 + c] = b[c];
}

// node linears via MFMA: grid = n_tiles*4, block 256 (4 waves)
__global__ void __launch_bounds__(256) k_node_mfma(const float* __restrict__ x,
    const unsigned short* __restrict__ wallf, const float* __restrict__ ball,
    unsigned short* __restrict__ qb, unsigned short* __restrict__ kb,
    unsigned short* __restrict__ vb, float* __restrict__ xr) {
  __shared__ unsigned short sA[128*128];   // 32KB, chunk-swizzled bf16
  int mat = blockIdx.x & 3;
  int n0 = (blockIdx.x >> 2) * 128;
  for (int i = 0; i < 8; ++i) {
    int c = threadIdx.x + i*256;       // 0..2047
    int row = c >> 4, ch = c & 15;
    int sw = (ch & 8) | ((ch & 7) ^ (row & 7));
    unsigned short tmp[8];
    if (n0 + row < NN) {
      const float* src = x + (size_t)(n0+row)*128 + ch*8;
      float4 f0 = *(const float4*)src;
      float4 f1 = *(const float4*)(src + 4);
      tmp[0]=f2b(f0.x); tmp[1]=f2b(f0.y); tmp[2]=f2b(f0.z); tmp[3]=f2b(f0.w);
      tmp[4]=f2b(f1.x); tmp[5]=f2b(f1.y); tmp[6]=f2b(f1.z); tmp[7]=f2b(f1.w);
    } else {
      #pragma unroll
      for (int j = 0; j < 8; ++j) tmp[j] = 0;
    }
    *(uint4*)&sA[row*128 + sw*8] = *(const uint4*)tmp;
  }
  __syncthreads();
  int l = threadIdx.x & 63, w = threadIdx.x >> 6;
  int g = l >> 4, ln = l & 15;
  f32x4 acc[2][8];
  #pragma unroll
  for (int rt = 0; rt < 2; ++rt)
    #pragma unroll
    for (int ct = 0; ct < 8; ++ct) acc[rt][ct] = (f32x4){0.f,0.f,0.f,0.f};
  for (int s = 0; s < 4; ++s) {
    bf16x8 wf[8];
    #pragma unroll
    for (int ct = 0; ct < 8; ++ct)
      wf[ct] = *(const bf16x8*)(wallf + ((((size_t)(mat*8+ct))*4 + s)*64 + l)*8);
    bf16x8 bfr[2];
    #pragma unroll
    for (int rt = 0; rt < 2; ++rt) {
      int row = w*32 + rt*16 + ln;
      int ch = s*4 + g;
      int sw = (ch & 8) | ((ch & 7) ^ (row & 7));
      bfr[rt] = *(const bf16x8*)&sA[row*128 + sw*8];
    }
    #pragma unroll
    for (int rt = 0; rt < 2; ++rt)
      #pragma unroll
      for (int ct = 0; ct < 8; ++ct)
        acc[rt][ct] = __builtin_amdgcn_mfma_f32_16x16x32_bf16(wf[ct], bfr[rt], acc[rt][ct], 0, 0, 0);
  }
  #pragma unroll
  for (int rt = 0; rt < 2; ++rt) {
    int node = n0 + w*32 + rt*16 + ln;
    if (node >= NN) continue;
    #pragma unroll
    for (int ct = 0; ct < 8; ++ct) {
      int c0 = ct*16 + g*4;
      float4 bi = *(const float4*)(ball + mat*128 + c0);
      float v0 = acc[rt][ct][0] + bi.x, v1 = acc[rt][ct][1] + bi.y;
      float v2 = acc[rt][ct][2] + bi.z, v3 = acc[rt][ct][3] + bi.w;
      if (mat == 3) {
        float4 o = {v0, v1, v2, v3};
        *(float4*)(xr + (size_t)node*128 + c0) = o;
      } else {
        unsigned short* dst = (mat==0) ? qb : (mat==1) ? kb : vb;
        unsigned short o[4] = {f2b(v0), f2b(v1), f2b(v2), f2b(v3)};
        *(uint2*)(dst + (size_t)node*128 + c0) = *(const uint2*)o;
      }
    }
  }
}

// edge GEMM via MFMA, output rows written to CSR-sorted positions
__global__ void __launch_bounds__(256) k_egemm_mfma(const float* __restrict__ es,
    const unsigned short* __restrict__ wcef, const float* __restrict__ bce,
    const int* __restrict__ pos, unsigned short* __restrict__ eb) {
  __shared__ unsigned short sA[128*64];    // 16KB, chunk-swizzled bf16
  int e0 = blockIdx.x * 128;
  for (int i = 0; i < 4; ++i) {
    int c = threadIdx.x + i*256;       // 0..1023
    int row = c >> 3, ch = c & 7;
    int sw = ch ^ (row & 7);
    const float* src = es + (size_t)(e0+row)*64 + ch*8;
    float4 f0 = *(const float4*)src;
    float4 f1 = *(const float4*)(src + 4);
    unsigned short tmp[8];
    tmp[0]=f2b(f0.x); tmp[1]=f2b(f0.y); tmp[2]=f2b(f0.z); tmp[3]=f2b(f0.w);
    tmp[4]=f2b(f1.x); tmp[5]=f2b(f1.y); tmp[6]=f2b(f1.z); tmp[7]=f2b(f1.w);
    *(uint4*)&sA[row*64 + sw*8] = *(const uint4*)tmp;
  }
  __syncthreads();
  int l = threadIdx.x & 63, w = threadIdx.x >> 6;
  int g = l >> 4, ln = l & 15;
  f32x4 acc[2][8];
  #pragma unroll
  for (int rt = 0; rt < 2; ++rt)
    #pragma unroll
    for (int ct = 0; ct < 8; ++ct) acc[rt][ct] = (f32x4){0.f,0.f,0.f,0.f};
  #pragma unroll
  for (int s = 0; s < 2; ++s) {
    bf16x8 wf[8];
    #pragma unroll
    for (int ct = 0; ct < 8; ++ct)
      wf[ct] = *(const bf16x8*)(wcef + (((size_t)(ct*2+s))*64 + l)*8);
    bf16x8 bfr[2];
    #pragma unroll
    for (int rt = 0; rt < 2; ++rt) {
      int row = w*32 + rt*16 + ln;
      int ch = (s*4 + g) ^ (row & 7);
      bfr[rt] = *(const bf16x8*)&sA[row*64 + ch*8];
    }
    #pragma unroll
    for (int rt = 0; rt < 2; ++rt)
      #pragma unroll
      for (int ct = 0; ct < 8; ++ct)
        acc[rt][ct] = __builtin_amdgcn_mfma_f32_16x16x32_bf16(wf[ct], bfr[rt], acc[rt][ct], 0, 0, 0);
  }
  #pragma unroll
  for (int rt = 0; rt < 2; ++rt) {
    int edge = e0 + w*32 + rt*16 + ln;
    int prow = pos[edge];
    unsigned short* dst = eb + (size_t)prow*128;
    #pragma unroll
    for (int ct = 0; ct < 8; ++ct) {
      int c0 = ct*16 + g*4;
      float4 bi = *(const float4*)(bce + c0);
      unsigned short o[4] = {f2b(acc[rt][ct][0]+bi.x), f2b(acc[rt][ct][1]+bi.y),
                             f2b(acc[rt][ct][2]+bi.z), f2b(acc[rt][ct][3]+bi.w)};
      *(uint2*)(dst + c0) = *(const uint2*)o;
    }
  }
}

// -------- CSR build --------
__global__ void __launch_bounds__(256) k_hist(const int* __restrict__ ei, int* __restrict__ cnt) {
  int t = blockIdx.x * 256 + threadIdx.x;
  if (t < NE) atomicAdd(&cnt[ei[NE + t]], 1);
}

__global__ void __launch_bounds__(256) k_scanA(const int* __restrict__ cnt,
    int* __restrict__ off, int* __restrict__ bsum) {
  __shared__ int s[256];
  int i = blockIdx.x * 256 + threadIdx.x;
  int v = (i < NN) ? cnt[i] : 0;
  s[threadIdx.x] = v;
  __syncthreads();
  #pragma unroll
  for (int d = 1; d < 256; d <<= 1) {
    int t = (threadIdx.x >= d) ? s[threadIdx.x - d] : 0;
    __syncthreads();
    s[threadIdx.x] += t;
    __syncthreads();
  }
  if (i < NN) off[i] = s[threadIdx.x] - v;
  if (threadIdx.x == 255) bsum[blockIdx.x] = s[255];
}

__global__ void __launch_bounds__(256) k_scanB(int* __restrict__ bsum, int nb) {
  __shared__ int s[256];
  int v = (threadIdx.x < nb) ? bsum[threadIdx.x] : 0;
  s[threadIdx.x] = v;
  __syncthreads();
  #pragma unroll
  for (int d = 1; d < 256; d <<= 1) {
    int t = (threadIdx.x >= d) ? s[threadIdx.x - d] : 0;
    __syncthreads();
    s[threadIdx.x] += t;
    __syncthreads();
  }
  if (threadIdx.x < nb) bsum[threadIdx.x] = s[threadIdx.x] - v;
}

__global__ void __launch_bounds__(256) k_scanC(int* __restrict__ off,
    const int* __restrict__ bsum, int* __restrict__ cur) {
  int i = blockIdx.x * 256 + threadIdx.x;
  if (i < NN) {
    int o = off[i] + bsum[blockIdx.x];
    off[i] = o;
    cur[i] = o;
  }
}

// also records each edge's CSR slot (pos) and the slot's source node (srcs)
__global__ void __launch_bounds__(256) k_scatter(const int* __restrict__ ei,
    int* __restrict__ cur, int* __restrict__ pos, int* __restrict__ srcs) {
  int t = blockIdx.x * 256 + threadIdx.x;
  if (t < NE) {
    int d = ei[NE + t];
    int p = atomicAdd(&cur[d], 1);
    pos[t] = p;
    srcs[p] = ei[t];
  }
}

// -------- fused attention gather + beta-gate + LN + residual ReLU --------
// one wave per node; lane l owns channels 2l, 2l+1; head = l>>3
// eb rows are CSR-sorted: node n's edges are rows off[n]..off[n]+cnt[n]-1 (sequential)
__global__ void __launch_bounds__(256) k_attn(
    const int* __restrict__ off, const int* __restrict__ cnt,
    const int* __restrict__ srcs,
    const unsigned short* __restrict__ qb, const unsigned short* __restrict__ kb,
    const unsigned short* __restrict__ vb, const unsigned short* __restrict__ eb,
    const float* __restrict__ xr, const float* __restrict__ x,
    const float* __restrict__ Wb, const float* __restrict__ ln_g,
    const float* __restrict__ ln_b, float* __restrict__ out) {
  int wid = threadIdx.x >> 6, lane = threadIdx.x & 63;
  int n = blockIdx.x * 4 + wid;
  if (n >= NN) return;
  int c = lane * 2;

  unsigned int qu = *(const unsigned int*)(qb + (size_t)n*128 + c);
  float q0 = b2f((unsigned short)(qu & 0xffffu)), q1 = b2f((unsigned short)(qu >> 16));

  int start = off[n], m = cnt[n];
  const int* sp = srcs + start;
  const unsigned short* ep = eb + (size_t)start*128 + c;
  float acc0 = 0.f, acc1 = 0.f, den = 0.f;

  auto body = [&](unsigned int ku, unsigned int eu, unsigned int vu) {
    float e0 = b2f((unsigned short)(eu & 0xffffu)), e1 = b2f((unsigned short)(eu >> 16));
    float p = q0*(b2f((unsigned short)(ku & 0xffffu)) + e0)
            + q1*(b2f((unsigned short)(ku >> 16)) + e1);
    p += __shfl_xor(p, 1);
    p += __shfl_xor(p, 2);
    p += __shfl_xor(p, 4);
    float a = __expf(p * 0.25f);
    den  += a;
    acc0 += a * (b2f((unsigned short)(vu & 0xffffu)) + e0);
    acc1 += a * (b2f((unsigned short)(vu >> 16)) + e1);
  };

  int i = 0;
  for (; i + 2 <= m; i += 2) {
    int sA = sp[i], sB = sp[i+1];
    unsigned int euA = *(const unsigned int*)(ep + (size_t)i*128);
    unsigned int euB = *(const unsigned int*)(ep + (size_t)(i+1)*128);
    unsigned int kuA = *(const unsigned int*)(kb + (size_t)sA*128 + c);
    unsigned int vuA = *(const unsigned int*)(vb + (size_t)sA*128 + c);
    unsigned int kuB = *(const unsigned int*)(kb + (size_t)sB*128 + c);
    unsigned int vuB = *(const unsigned int*)(vb + (size_t)sB*128 + c);
    body(kuA, euA, vuA);
    body(kuB, euB, vuB);
  }
  if (i < m) {
    int sA = sp[i];
    unsigned int euA = *(const unsigned int*)(ep + (size_t)i*128);
    unsigned int kuA = *(const unsigned int*)(kb + (size_t)sA*128 + c);
    unsigned int vuA = *(const unsigned int*)(vb + (size_t)sA*128 + c);
    body(kuA, euA, vuA);
  }

  float inv = (m > 0) ? 1.f / den : 0.f;
  float o0 = acc0 * inv, o1 = acc1 * inv;

  // epilogue
  float2 r = *(const float2*)(xr + (size_t)n*128 + c);
  float p = o0*Wb[c] + o1*Wb[c+1] + r.x*Wb[128+c] + r.y*Wb[128+c+1]
          + (o0-r.x)*Wb[256+c] + (o1-r.y)*Wb[256+c+1];
  #pragma unroll
  for (int offs = 32; offs > 0; offs >>= 1) p += __shfl_xor(p, offs);
  float beta = 1.f / (1.f + __expf(-p));
  float g0 = beta*r.x + (1.f-beta)*o0;
  float g1 = beta*r.y + (1.f-beta)*o1;
  float msum = g0 + g1;
  #pragma unroll
  for (int offs = 32; offs > 0; offs >>= 1) msum += __shfl_xor(msum, offs);
  msum *= (1.f/128.f);
  float d0 = g0 - msum, d1 = g1 - msum;
  float vv = d0*d0 + d1*d1;
  #pragma unroll
  for (int offs = 32; offs > 0; offs >>= 1) vv += __shfl_xor(vv, offs);
  vv *= (1.f/128.f);
  float rs = rsqrtf(vv + 1e-5f);
  float n0 = d0*rs*ln_g[c]   + ln_b[c];
  float n1 = d1*rs*ln_g[c+1] + ln_b[c+1];
  float2 xv = *(const float2*)(x + (size_t)n*128 + c);
  float2 res;
  res.x = xv.x + fmaxf(n0, 0.f);
  res.y = xv.y + fmaxf(n1, 0.f);
  *(float2*)(out + (size_t)n*128 + c) = res;
}

extern "C" void kernel_launch(void* const* d_in, const int* in_sizes, int n_in,
                              void* d_out, int out_size, void* d_ws, size_t ws_size,
                              hipStream_t stream) {
  const float* node   = (const float*)d_in[0];
  const int*   ei     = (const int*)  d_in[1];
  const float* es     = (const float*)d_in[2];
  const float* W_edge = (const float*)d_in[3];
  const float* b_edge = (const float*)d_in[4];
  const float* Wq     = (const float*)d_in[5];
  const float* bq     = (const float*)d_in[6];
  const float* Wk     = (const float*)d_in[7];
  const float* bk     = (const float*)d_in[8];
  const float* Wv     = (const float*)d_in[9];
  const float* bv     = (const float*)d_in[10];
  const float* We     = (const float*)d_in[11];
  const float* Wskip  = (const float*)d_in[12];
  const float* bskip  = (const float*)d_in[13];
  const float* Wbeta  = (const float*)d_in[14];
  const float* ln_g   = (const float*)d_in[15];
  const float* ln_b   = (const float*)d_in[16];

  char* ws = (char*)d_ws;
  unsigned short* wce   = (unsigned short*)(ws + WS_WCE);
  float*          bce   = (float*)(ws + WS_BCE);
  unsigned short* wcef  = (unsigned short*)(ws + WS_WCEF);
  unsigned short* wallf = (unsigned short*)(ws + WS_WALLF);
  float*          ball  = (float*)(ws + WS_BALL);
  unsigned short* qb  = (unsigned short*)(ws + WS_QB);
  unsigned short* kb  = (unsigned short*)(ws + WS_KB);
  unsigned short* vb  = (unsigned short*)(ws + WS_VB);
  float*          xr  = (float*)(ws + WS_XR);
  unsigned short* eb  = (unsigned short*)(ws + WS_EB);
  int*            cnt = (int*)(ws + WS_CNT);
  int*            off = (int*)(ws + WS_OFF);
  int*            cur = (int*)(ws + WS_CUR);
  int*            bsm = (int*)(ws + WS_BSUM);
  int*            pos = (int*)(ws + WS_POS);
  int*            srcs= (int*)(ws + WS_SRCS);

  hipMemsetAsync(cnt, 0, (size_t)NN*4, stream);

  k_prep<<<64, 128, 0, stream>>>(W_edge, b_edge, We, wce, bce);
  k_pack_wce<<<16, 64, 0, stream>>>(wce, wcef);
  k_pack_wall<<<128, 64, 0, stream>>>(Wq, Wk, Wv, Wskip, wallf);
  k_pack_bias<<<4, 128, 0, stream>>>(bq, bk, bv, bskip, ball);

  const int nbScan = (NN + 255)/256;  // 196
  k_hist<<<(NE + 255)/256, 256, 0, stream>>>(ei, cnt);
  k_scanA<<<nbScan, 256, 0, stream>>>(cnt, off, bsm);
  k_scanB<<<1, 256, 0, stream>>>(bsm, nbScan);
  k_scanC<<<nbScan, 256, 0, stream>>>(off, bsm, cur);
  k_scatter<<<(NE + 255)/256, 256, 0, stream>>>(ei, cur, pos, srcs);

  const int ntiles = (NN + 127) / 128;  // 391
  k_node_mfma<<<ntiles*4, 256, 0, stream>>>(node, wallf, ball, qb, kb, vb, xr);
  k_egemm_mfma<<<NE/128, 256, 0, stream>>>(es, wcef, bce, pos, eb);

  k_attn<<<(NN + 3)/4, 256, 0, stream>>>(off, cnt, srcs, qb, kb, vb, eb,
                                         xr, node, Wbeta, ln_g, ln_b, (float*)d_out);
}

// Round 5
// 350.432 us; speedup vs baseline: 18.1569x; 1.1327x over previous
//
#include <hip/hip_runtime.h>
#include <cstdint>
#include <cstddef>

#define NN 50000
#define NE 800000
// DN=128, DE=64, H=8, C=16

typedef short bf16x8 __attribute__((ext_vector_type(8)));
typedef float f32x4 __attribute__((ext_vector_type(4)));

__device__ __forceinline__ float b2f(unsigned short s) {
  union { unsigned int u; float f; } x; x.u = ((unsigned int)s) << 16; return x.f;
}
__device__ __forceinline__ unsigned short f2b(float f) {
  union { float f; unsigned int u; } x; x.f = f;
  unsigned int r = x.u + 0x7FFFu + ((x.u >> 16) & 1u);
  return (unsigned short)(r >> 16);
}

// ---------------- ws layout (bytes) ----------------
#define WS_WCE    0u          // bf16 [64][128] (16KB)
#define WS_BCE    16384u      // f32 [128]
#define WS_WCEF   20480u      // bf16 frags 8ct*2s*64l*8j (16KB)
#define WS_WALLF  40960u      // bf16 frags 4m*8ct*4s*64l*8j (128KB)
#define WS_BALL   172032u     // f32 [512]
#define WS_QB     180224u     // bf16 [NN][128]
#define WS_KB     12980224u   // bf16 [NN][128]
#define WS_VB     25780224u   // bf16 [NN][128]
#define WS_XR     38580224u   // f32  [NN][128]
#define WS_EB     64180224u   // bf16 [NE][128] (CSR-sorted rows)
#define WS_CNT    268980224u  // int [NN]
#define WS_OFF    269180224u  // int [NN]
#define WS_CUR    269380224u  // int [NN]
#define WS_BSUM   269580224u  // int [256]
#define WS_POS    269584320u  // int [NE]
#define WS_SRCS   272784320u  // int [NE]
// end = 275,984,320 B

// W_ce = W_edge @ We (64x128, bf16), b_ce = b_edge @ We (f32)
__global__ void k_prep(const float* __restrict__ W_edge, const float* __restrict__ b_edge,
                       const float* __restrict__ We, unsigned short* __restrict__ wce,
                       float* __restrict__ bce) {
  int i = blockIdx.x;       // 0..63
  int j = threadIdx.x;      // 0..127
  float s = 0.f;
  for (int m = 0; m < 64; ++m) s += W_edge[i*64+m] * We[m*128+j];
  wce[i*128+j] = f2b(s);
  if (i == 0) {
    float bb = 0.f;
    for (int m = 0; m < 64; ++m) bb += b_edge[m] * We[m*128+j];
    bce[j] = bb;
  }
}

// pack wce [64][128] into A-frag layout
__global__ void k_pack_wce(const unsigned short* __restrict__ wce, unsigned short* __restrict__ wcef) {
  int fb = blockIdx.x;           // 0..15
  int ct = fb >> 1, s = fb & 1;
  int l = threadIdx.x;           // 0..63
  unsigned short* dst = wcef + (((size_t)(ct*2+s))*64 + l)*8;
  int col = ct*16 + (l & 15);
  int k0 = s*32 + (l >> 4)*8;
  #pragma unroll
  for (int j = 0; j < 8; ++j) dst[j] = wce[(k0+j)*128 + col];
}

// pack Wq/Wk/Wv/Wskip (fp32 [128][128], y=x@W layout) into bf16 A-frags
__global__ void k_pack_wall(const float* __restrict__ Wq, const float* __restrict__ Wk,
                            const float* __restrict__ Wv, const float* __restrict__ Ws,
                            unsigned short* __restrict__ wallf) {
  int fb = blockIdx.x;           // 0..127
  int mat = fb >> 5, ct = (fb >> 2) & 7, s = fb & 3;
  int l = threadIdx.x;
  const float* W = (mat==0) ? Wq : (mat==1) ? Wk : (mat==2) ? Wv : Ws;
  unsigned short* dst = wallf + ((((size_t)(mat*8+ct))*4 + s)*64 + l)*8;
  int col = ct*16 + (l & 15);
  int k0 = s*32 + (l >> 4)*8;
  #pragma unroll
  for (int j = 0; j < 8; ++j) dst[j] = f2b(W[(k0+j)*128 + col]);
}

__global__ void k_pack_bias(const float* __restrict__ bq, const float* __restrict__ bk,
                            const float* __restrict__ bv, const float* __restrict__ bs,
                            float* __restrict__ ball) {
  int m = blockIdx.x, c = threadIdx.x;
  const float* b = (m==0) ? bq : (m==1) ? bk : (m==2) ? bv : bs;
  ball[m*128 + c] = b[c];
}

// node linears via MFMA: grid = n_tiles*4, block 256 (4 waves)
__global__ void __launch_bounds__(256) k_node_mfma(const float* __restrict__ x,
    const unsigned short* __restrict__ wallf, const float* __restrict__ ball,
    unsigned short* __restrict__ qb, unsigned short* __restrict__ kb,
    unsigned short* __restrict__ vb, float* __restrict__ xr) {
  __shared__ unsigned short sA[128*128];   // 32KB, chunk-swizzled bf16
  int mat = blockIdx.x & 3;
  int n0 = (blockIdx.x >> 2) * 128;
  for (int i = 0; i < 8; ++i) {
    int c = threadIdx.x + i*256;       // 0..2047
    int row = c >> 4, ch = c & 15;
    int sw = (ch & 8) | ((ch & 7) ^ (row & 7));
    unsigned short tmp[8];
    if (n0 + row < NN) {
      const float* src = x + (size_t)(n0+row)*128 + ch*8;
      float4 f0 = *(const float4*)src;
      float4 f1 = *(const float4*)(src + 4);
      tmp[0]=f2b(f0.x); tmp[1]=f2b(f0.y); tmp[2]=f2b(f0.z); tmp[3]=f2b(f0.w);
      tmp[4]=f2b(f1.x); tmp[5]=f2b(f1.y); tmp[6]=f2b(f1.z); tmp[7]=f2b(f1.w);
    } else {
      #pragma unroll
      for (int j = 0; j < 8; ++j) tmp[j] = 0;
    }
    *(uint4*)&sA[row*128 + sw*8] = *(const uint4*)tmp;
  }
  __syncthreads();
  int l = threadIdx.x & 63, w = threadIdx.x >> 6;
  int g = l >> 4, ln = l & 15;
  f32x4 acc[2][8];
  #pragma unroll
  for (int rt = 0; rt < 2; ++rt)
    #pragma unroll
    for (int ct = 0; ct < 8; ++ct) acc[rt][ct] = (f32x4){0.f,0.f,0.f,0.f};
  for (int s = 0; s < 4; ++s) {
    bf16x8 wf[8];
    #pragma unroll
    for (int ct = 0; ct < 8; ++ct)
      wf[ct] = *(const bf16x8*)(wallf + ((((size_t)(mat*8+ct))*4 + s)*64 + l)*8);
    bf16x8 bfr[2];
    #pragma unroll
    for (int rt = 0; rt < 2; ++rt) {
      int row = w*32 + rt*16 + ln;
      int ch = s*4 + g;
      int sw = (ch & 8) | ((ch & 7) ^ (row & 7));
      bfr[rt] = *(const bf16x8*)&sA[row*128 + sw*8];
    }
    #pragma unroll
    for (int rt = 0; rt < 2; ++rt)
      #pragma unroll
      for (int ct = 0; ct < 8; ++ct)
        acc[rt][ct] = __builtin_amdgcn_mfma_f32_16x16x32_bf16(wf[ct], bfr[rt], acc[rt][ct], 0, 0, 0);
  }
  #pragma unroll
  for (int rt = 0; rt < 2; ++rt) {
    int node = n0 + w*32 + rt*16 + ln;
    if (node >= NN) continue;
    #pragma unroll
    for (int ct = 0; ct < 8; ++ct) {
      int c0 = ct*16 + g*4;
      float4 bi = *(const float4*)(ball + mat*128 + c0);
      float v0 = acc[rt][ct][0] + bi.x, v1 = acc[rt][ct][1] + bi.y;
      float v2 = acc[rt][ct][2] + bi.z, v3 = acc[rt][ct][3] + bi.w;
      if (mat == 3) {
        float4 o = {v0, v1, v2, v3};
        *(float4*)(xr + (size_t)node*128 + c0) = o;
      } else {
        unsigned short* dst = (mat==0) ? qb : (mat==1) ? kb : vb;
        unsigned short o[4] = {f2b(v0), f2b(v1), f2b(v2), f2b(v3)};
        *(uint2*)(dst + (size_t)node*128 + c0) = *(const uint2*)o;
      }
    }
  }
}

// edge GEMM via MFMA; CSR-scattered rows staged through LDS so every global
// store instruction covers 4 full 256B rows (16 lanes x 16B contiguous per row)
__global__ void __launch_bounds__(256) k_egemm_mfma(const float* __restrict__ es,
    const unsigned short* __restrict__ wcef, const float* __restrict__ bce,
    const int* __restrict__ pos, unsigned short* __restrict__ eb) {
  __shared__ unsigned short sA[128*64];    // 16KB input staging (chunk-swizzled)
  __shared__ unsigned short sO[128*128];   // 32KB output staging (chunk-swizzled)
  int e0 = blockIdx.x * 128;
  for (int i = 0; i < 4; ++i) {
    int c = threadIdx.x + i*256;       // 0..1023
    int row = c >> 3, ch = c & 7;
    int sw = ch ^ (row & 7);
    const float* src = es + (size_t)(e0+row)*64 + ch*8;
    float4 f0 = *(const float4*)src;
    float4 f1 = *(const float4*)(src + 4);
    unsigned short tmp[8];
    tmp[0]=f2b(f0.x); tmp[1]=f2b(f0.y); tmp[2]=f2b(f0.z); tmp[3]=f2b(f0.w);
    tmp[4]=f2b(f1.x); tmp[5]=f2b(f1.y); tmp[6]=f2b(f1.z); tmp[7]=f2b(f1.w);
    *(uint4*)&sA[row*64 + sw*8] = *(const uint4*)tmp;
  }
  __syncthreads();
  int l = threadIdx.x & 63, w = threadIdx.x >> 6;
  int g = l >> 4, ln = l & 15;
  f32x4 acc[2][8];
  #pragma unroll
  for (int rt = 0; rt < 2; ++rt)
    #pragma unroll
    for (int ct = 0; ct < 8; ++ct) acc[rt][ct] = (f32x4){0.f,0.f,0.f,0.f};
  #pragma unroll
  for (int s = 0; s < 2; ++s) {
    bf16x8 wf[8];
    #pragma unroll
    for (int ct = 0; ct < 8; ++ct)
      wf[ct] = *(const bf16x8*)(wcef + (((size_t)(ct*2+s))*64 + l)*8);
    bf16x8 bfr[2];
    #pragma unroll
    for (int rt = 0; rt < 2; ++rt) {
      int row = w*32 + rt*16 + ln;
      int ch = (s*4 + g) ^ (row & 7);
      bfr[rt] = *(const bf16x8*)&sA[row*64 + ch*8];
    }
    #pragma unroll
    for (int rt = 0; rt < 2; ++rt)
      #pragma unroll
      for (int ct = 0; ct < 8; ++ct)
        acc[rt][ct] = __builtin_amdgcn_mfma_f32_16x16x32_bf16(wf[ct], bfr[rt], acc[rt][ct], 0, 0, 0);
  }
  // stage D-frags (+bias, bf16) into swizzled LDS
  #pragma unroll
  for (int rt = 0; rt < 2; ++rt) {
    int row = w*32 + rt*16 + ln;
    #pragma unroll
    for (int ct = 0; ct < 8; ++ct) {
      int c0 = ct*16 + g*4;
      float4 bi = *(const float4*)(bce + c0);
      unsigned short o[4] = {f2b(acc[rt][ct][0]+bi.x), f2b(acc[rt][ct][1]+bi.y),
                             f2b(acc[rt][ct][2]+bi.z), f2b(acc[rt][ct][3]+bi.w)};
      int ch = ct*2 + (g >> 1);                       // 16B chunk 0..15
      int sw = (ch & 8) | ((ch & 7) ^ (row & 7));
      *(uint2*)&sO[row*128 + sw*8 + (g & 1)*4] = *(const uint2*)o;
    }
  }
  __syncthreads();
  // readback: 4 full rows per store instruction (16 lanes x 16B each)
  int rrow = threadIdx.x >> 4;   // 0..15
  int rch  = threadIdx.x & 15;
  #pragma unroll
  for (int it = 0; it < 8; ++it) {
    int r = it*16 + rrow;
    int sw = (rch & 8) | ((rch & 7) ^ (r & 7));
    uint4 val = *(const uint4*)&sO[r*128 + sw*8];
    int prow = pos[e0 + r];
    *(uint4*)(eb + (size_t)prow*128 + rch*8) = val;
  }
}

// -------- CSR build --------
__global__ void __launch_bounds__(256) k_hist(const int* __restrict__ ei, int* __restrict__ cnt) {
  int t = blockIdx.x * 256 + threadIdx.x;
  if (t < NE) atomicAdd(&cnt[ei[NE + t]], 1);
}

__global__ void __launch_bounds__(256) k_scanA(const int* __restrict__ cnt,
    int* __restrict__ off, int* __restrict__ bsum) {
  __shared__ int s[256];
  int i = blockIdx.x * 256 + threadIdx.x;
  int v = (i < NN) ? cnt[i] : 0;
  s[threadIdx.x] = v;
  __syncthreads();
  #pragma unroll
  for (int d = 1; d < 256; d <<= 1) {
    int t = (threadIdx.x >= d) ? s[threadIdx.x - d] : 0;
    __syncthreads();
    s[threadIdx.x] += t;
    __syncthreads();
  }
  if (i < NN) off[i] = s[threadIdx.x] - v;
  if (threadIdx.x == 255) bsum[blockIdx.x] = s[255];
}

__global__ void __launch_bounds__(256) k_scanB(int* __restrict__ bsum, int nb) {
  __shared__ int s[256];
  int v = (threadIdx.x < nb) ? bsum[threadIdx.x] : 0;
  s[threadIdx.x] = v;
  __syncthreads();
  #pragma unroll
  for (int d = 1; d < 256; d <<= 1) {
    int t = (threadIdx.x >= d) ? s[threadIdx.x - d] : 0;
    __syncthreads();
    s[threadIdx.x] += t;
    __syncthreads();
  }
  if (threadIdx.x < nb) bsum[threadIdx.x] = s[threadIdx.x] - v;
}

__global__ void __launch_bounds__(256) k_scanC(int* __restrict__ off,
    const int* __restrict__ bsum, int* __restrict__ cur) {
  int i = blockIdx.x * 256 + threadIdx.x;
  if (i < NN) {
    int o = off[i] + bsum[blockIdx.x];
    off[i] = o;
    cur[i] = o;
  }
}

// records each edge's CSR slot (pos) and the slot's source node (srcs)
__global__ void __launch_bounds__(256) k_scatter(const int* __restrict__ ei,
    int* __restrict__ cur, int* __restrict__ pos, int* __restrict__ srcs) {
  int t = blockIdx.x * 256 + threadIdx.x;
  if (t < NE) {
    int d = ei[NE + t];
    int p = atomicAdd(&cur[d], 1);
    pos[t] = p;
    srcs[p] = ei[t];
  }
}

// -------- fused attention gather + beta-gate + LN + residual ReLU --------
__global__ void __launch_bounds__(256) k_attn(
    const int* __restrict__ off, const int* __restrict__ cnt,
    const int* __restrict__ srcs,
    const unsigned short* __restrict__ qb, const unsigned short* __restrict__ kb,
    const unsigned short* __restrict__ vb, const unsigned short* __restrict__ eb,
    const float* __restrict__ xr, const float* __restrict__ x,
    const float* __restrict__ Wb, const float* __restrict__ ln_g,
    const float* __restrict__ ln_b, float* __restrict__ out) {
  int wid = threadIdx.x >> 6, lane = threadIdx.x & 63;
  int n = blockIdx.x * 4 + wid;
  if (n >= NN) return;
  int c = lane * 2;

  unsigned int qu = *(const unsigned int*)(qb + (size_t)n*128 + c);
  float q0 = b2f((unsigned short)(qu & 0xffffu)), q1 = b2f((unsigned short)(qu >> 16));

  int start = off[n], m = cnt[n];
  const int* sp = srcs + start;
  const unsigned short* ep = eb + (size_t)start*128 + c;
  float acc0 = 0.f, acc1 = 0.f, den = 0.f;

  auto body = [&](unsigned int ku, unsigned int eu, unsigned int vu) {
    float e0 = b2f((unsigned short)(eu & 0xffffu)), e1 = b2f((unsigned short)(eu >> 16));
    float p = q0*(b2f((unsigned short)(ku & 0xffffu)) + e0)
            + q1*(b2f((unsigned short)(ku >> 16)) + e1);
    p += __shfl_xor(p, 1);
    p += __shfl_xor(p, 2);
    p += __shfl_xor(p, 4);
    float a = __expf(p * 0.25f);
    den  += a;
    acc0 += a * (b2f((unsigned short)(vu & 0xffffu)) + e0);
    acc1 += a * (b2f((unsigned short)(vu >> 16)) + e1);
  };

  int i = 0;
  for (; i + 2 <= m; i += 2) {
    int sA = sp[i], sB = sp[i+1];
    unsigned int euA = *(const unsigned int*)(ep + (size_t)i*128);
    unsigned int euB = *(const unsigned int*)(ep + (size_t)(i+1)*128);
    unsigned int kuA = *(const unsigned int*)(kb + (size_t)sA*128 + c);
    unsigned int vuA = *(const unsigned int*)(vb + (size_t)sA*128 + c);
    unsigned int kuB = *(const unsigned int*)(kb + (size_t)sB*128 + c);
    unsigned int vuB = *(const unsigned int*)(vb + (size_t)sB*128 + c);
    body(kuA, euA, vuA);
    body(kuB, euB, vuB);
  }
  if (i < m) {
    int sA = sp[i];
    unsigned int euA = *(const unsigned int*)(ep + (size_t)i*128);
    unsigned int kuA = *(const unsigned int*)(kb + (size_t)sA*128 + c);
    unsigned int vuA = *(const unsigned int*)(vb + (size_t)sA*128 + c);
    body(kuA, euA, vuA);
  }

  float inv = (m > 0) ? 1.f / den : 0.f;
  float o0 = acc0 * inv, o1 = acc1 * inv;

  float2 r = *(const float2*)(xr + (size_t)n*128 + c);
  float p = o0*Wb[c] + o1*Wb[c+1] + r.x*Wb[128+c] + r.y*Wb[128+c+1]
          + (o0-r.x)*Wb[256+c] + (o1-r.y)*Wb[256+c+1];
  #pragma unroll
  for (int offs = 32; offs > 0; offs >>= 1) p += __shfl_xor(p, offs);
  float beta = 1.f / (1.f + __expf(-p));
  float g0 = beta*r.x + (1.f-beta)*o0;
  float g1 = beta*r.y + (1.f-beta)*o1;
  float msum = g0 + g1;
  #pragma unroll
  for (int offs = 32; offs > 0; offs >>= 1) msum += __shfl_xor(msum, offs);
  msum *= (1.f/128.f);
  float d0 = g0 - msum, d1 = g1 - msum;
  float vv = d0*d0 + d1*d1;
  #pragma unroll
  for (int offs = 32; offs > 0; offs >>= 1) vv += __shfl_xor(vv, offs);
  vv *= (1.f/128.f);
  float rs = rsqrtf(vv + 1e-5f);
  float n0 = d0*rs*ln_g[c]   + ln_b[c];
  float n1 = d1*rs*ln_g[c+1] + ln_b[c+1];
  float2 xv = *(const float2*)(x + (size_t)n*128 + c);
  float2 res;
  res.x = xv.x + fmaxf(n0, 0.f);
  res.y = xv.y + fmaxf(n1, 0.f);
  *(float2*)(out + (size_t)n*128 + c) = res;
}

extern "C" void kernel_launch(void* const* d_in, const int* in_sizes, int n_in,
                              void* d_out, int out_size, void* d_ws, size_t ws_size,
                              hipStream_t stream) {
  const float* node   = (const float*)d_in[0];
  const int*   ei     = (const int*)  d_in[1];
  const float* es     = (const float*)d_in[2];
  const float* W_edge = (const float*)d_in[3];
  const float* b_edge = (const float*)d_in[4];
  const float* Wq     = (const float*)d_in[5];
  const float* bq     = (const float*)d_in[6];
  const float* Wk     = (const float*)d_in[7];
  const float* bk     = (const float*)d_in[8];
  const float* Wv     = (const float*)d_in[9];
  const float* bv     = (const float*)d_in[10];
  const float* We     = (const float*)d_in[11];
  const float* Wskip  = (const float*)d_in[12];
  const float* bskip  = (const float*)d_in[13];
  const float* Wbeta  = (const float*)d_in[14];
  const float* ln_g   = (const float*)d_in[15];
  const float* ln_b   = (const float*)d_in[16];

  char* ws = (char*)d_ws;
  unsigned short* wce   = (unsigned short*)(ws + WS_WCE);
  float*          bce   = (float*)(ws + WS_BCE);
  unsigned short* wcef  = (unsigned short*)(ws + WS_WCEF);
  unsigned short* wallf = (unsigned short*)(ws + WS_WALLF);
  float*          ball  = (float*)(ws + WS_BALL);
  unsigned short* qb  = (unsigned short*)(ws + WS_QB);
  unsigned short* kb  = (unsigned short*)(ws + WS_KB);
  unsigned short* vb  = (unsigned short*)(ws + WS_VB);
  float*          xr  = (float*)(ws + WS_XR);
  unsigned short* eb  = (unsigned short*)(ws + WS_EB);
  int*            cnt = (int*)(ws + WS_CNT);
  int*            off = (int*)(ws + WS_OFF);
  int*            cur = (int*)(ws + WS_CUR);
  int*            bsm = (int*)(ws + WS_BSUM);
  int*            pos = (int*)(ws + WS_POS);
  int*            srcs= (int*)(ws + WS_SRCS);

  hipMemsetAsync(cnt, 0, (size_t)NN*4, stream);

  k_prep<<<64, 128, 0, stream>>>(W_edge, b_edge, We, wce, bce);
  k_pack_wce<<<16, 64, 0, stream>>>(wce, wcef);
  k_pack_wall<<<128, 64, 0, stream>>>(Wq, Wk, Wv, Wskip, wallf);
  k_pack_bias<<<4, 128, 0, stream>>>(bq, bk, bv, bskip, ball);

  const int nbScan = (NN + 255)/256;  // 196
  k_hist<<<(NE + 255)/256, 256, 0, stream>>>(ei, cnt);
  k_scanA<<<nbScan, 256, 0, stream>>>(cnt, off, bsm);
  k_scanB<<<1, 256, 0, stream>>>(bsm, nbScan);
  k_scanC<<<nbScan, 256, 0, stream>>>(off, bsm, cur);
  k_scatter<<<(NE + 255)/256, 256, 0, stream>>>(ei, cur, pos, srcs);

  const int ntiles = (NN + 127) / 128;  // 391
  k_node_mfma<<<ntiles*4, 256, 0, stream>>>(node, wallf, ball, qb, kb, vb, xr);
  k_egemm_mfma<<<NE/128, 256, 0, stream>>>(es, wcef, bce, pos, eb);

  k_attn<<<(NN + 3)/4, 256, 0, stream>>>(off, cnt, srcs, qb, kb, vb, eb,
                                         xr, node, Wbeta, ln_g, ln_b, (float*)d_out);
}